// Round 13
// baseline (235.508 us; speedup 1.0000x reference)
//
#include <hip/hip_runtime.h>
#include <hip/hip_bf16.h>
#include <math.h>

#define B_N 16
#define C_IN 64
#define H_N 128
#define W_N 128
#define C_OUT 128
#define RS 8448      // bytes per row-slot: 66 cols * 128B
#define NSLOT 6

typedef __attribute__((ext_vector_type(8))) short short8v;   // 8 bf16
typedef __attribute__((ext_vector_type(4))) float float4v;

__device__ __forceinline__ unsigned short f2bf(float f) {
  union { float f; unsigned u; } c; c.f = f;
  unsigned u = c.u + 0x7fffu + ((c.u >> 16) & 1u);   // RNE
  return (unsigned short)(u >> 16);
}

// ---------------------------------------------------------------------------
// Prep: pack weights into per-lane B-fragment order (bf16) + w^2 partials.
// ---------------------------------------------------------------------------
__global__ __launch_bounds__(256) void scs_prep_w(
    const float* __restrict__ w, unsigned short* __restrict__ wf,
    float* __restrict__ partial)
{
  __shared__ float red[256];
  const int t    = threadIdx.x;
  const int gid  = blockIdx.x * 256 + t;
  const int frag = gid >> 6;
  const int l    = gid & 63;
  const int kh   = frag / 48;
  const int rem  = frag % 48;
  const int s    = rem >> 3;
  const int nt   = rem & 7;
  const int kb   = kh * 192 + s * 32 + (l >> 4) * 8;
  const int n    = nt * 16 + (l & 15);
  short8v pk;
  float ss = 0.f;
#pragma unroll
  for (int j = 0; j < 8; ++j) {
    const float v = w[(size_t)(kb + j) * C_OUT + n];
    ss = fmaf(v, v, ss);
    pk[j] = (short)f2bf(v);
  }
  *reinterpret_cast<short8v*>(wf + (size_t)frag * 512 + l * 8) = pk;
  red[t] = ss;
  __syncthreads();
  for (int off = 128; off > 0; off >>= 1) {
    if (t < off) red[t] += red[t + off];
    __syncthreads();
  }
  if (t == 0) partial[blockIdx.x] = red[0];
}

// ---------------------------------------------------------------------------
// Main v7: persistent-ish pipelined block. Block = (b, w-half, 8-row strip),
// grid 512. 6-slot circular LDS row window; per h-pair iteration:
//   issue loads(next 2 rows) -> MFMA(cur) -> pl -> cvt+LDS-write(next) ->
//   [lgkm barrier A] -> Ss reduce -> epilogue(cur) -> [lgkm barrier B]
// Raw barriers (no vmcnt drain): epilogue stores stay in flight across B.
// ---------------------------------------------------------------------------
#define LGKM_BARRIER()                                   \
  do {                                                   \
    asm volatile("s_waitcnt lgkmcnt(0)" ::: "memory");   \
    __builtin_amdgcn_s_barrier();                        \
    asm volatile("" ::: "memory");                       \
  } while (0)

__global__ __launch_bounds__(512, 4) void scs_main(
    const float* __restrict__ x, const unsigned short* __restrict__ wf,
    const float* __restrict__ bias, const float* __restrict__ q,
    const float* __restrict__ p, const float* __restrict__ partial,
    float* __restrict__ out)
{
  __shared__ alignas(16) char xT[NSLOT * RS];   // 50688B
  __shared__ float psacc[8][2][66];             // 4224B
  __shared__ float Ss[NSLOT][66];               // 1584B  (total 56.5KB)

  const int t   = threadIdx.x;
  const int l   = t & 63;
  const int wid = t >> 6;
  const int wm  = wid >> 2;        // 0..1 (M half: 32 pixels)
  const int wn  = wid & 3;         // 0..3 (N quarter: 32 couts)
  const int lr  = l & 15;
  const int lg  = l >> 4;
  const int bid = blockIdx.x;
  const int swz = (bid & 7) * 64 + (bid >> 3);  // bijective XCD remap (512%8==0)
  const int b     = swz >> 5;
  const int strip = (swz >> 1) & 15;
  const int w0    = (swz & 1) << 6;
  const int hs    = strip << 3;

  // scalars once per block
  float ssum = 0.f;
#pragma unroll
  for (int i = 0; i < 36; ++i) ssum += partial[i];
  const float nk = sqrtf(ssum);
  const float qe = __builtin_amdgcn_exp2f(q[0] * 1.4426950408889634f);
  const float pe = __builtin_amdgcn_exp2f(p[0] * 1.4426950408889634f);
  const float nlg_nkq = -__builtin_amdgcn_logf(nk + qe);
  const float bv0 = bias[wn * 32 + lr];
  const float bv1 = bias[wn * 32 + 16 + lr];

  // staging maps
  const int wl = t & 63, gg = t >> 6;
  const int jr_m    = wl + 1;
  const int xbyte_m = jr_m * 128 + ((gg * 16) ^ ((jr_m & 7) << 4));
  const int ee  = t & 1, erp = (t >> 1) & 1, eg = t >> 2;  // for t<32
  const int e_jr    = ee ? 65 : 0;
  const int e_gw    = w0 - 1 + ee * 65;
  const int e_xbyte = e_jr * 128 + ((eg * 16) ^ ((e_jr & 7) << 4));

  float xm[2][8];
  float xe[8];

#define STAGE_ISSUE(ar0_, ar1_)                                              \
  {                                                                          \
    _Pragma("unroll")                                                        \
    for (int rp = 0; rp < 2; ++rp) {                                         \
      const int ar_ = rp ? (ar1_) : (ar0_);                                  \
      if ((unsigned)ar_ < 128u) {                                            \
        const float* src_ = x + (((size_t)b * C_IN + gg * 8) * H_N + ar_) * W_N + w0 + wl; \
        _Pragma("unroll")                                                    \
        for (int j = 0; j < 8; ++j) xm[rp][j] = src_[(size_t)j * H_N * W_N]; \
      } else {                                                               \
        _Pragma("unroll")                                                    \
        for (int j = 0; j < 8; ++j) xm[rp][j] = 0.f;                         \
      }                                                                      \
    }                                                                        \
    if (t < 32) {                                                            \
      const int ar_ = erp ? (ar1_) : (ar0_);                                 \
      if (((unsigned)ar_ < 128u) && ((unsigned)e_gw < 128u)) {               \
        const float* src_ = x + (((size_t)b * C_IN + eg * 8) * H_N + ar_) * W_N + e_gw; \
        _Pragma("unroll")                                                    \
        for (int j = 0; j < 8; ++j) xe[j] = src_[(size_t)j * H_N * W_N];     \
      } else {                                                               \
        _Pragma("unroll")                                                    \
        for (int j = 0; j < 8; ++j) xe[j] = 0.f;                             \
      }                                                                      \
    }                                                                        \
  }

#define STAGE_COMMIT(ar0_, ar1_)                                             \
  {                                                                          \
    _Pragma("unroll")                                                        \
    for (int rp = 0; rp < 2; ++rp) {                                         \
      const int ar_   = rp ? (ar1_) : (ar0_);                                \
      const int slot_ = (ar_ + 7) % 6;                                       \
      float ss_ = 0.f;                                                       \
      _Pragma("unroll")                                                      \
      for (int j = 0; j < 8; ++j) ss_ = fmaf(xm[rp][j], xm[rp][j], ss_);     \
      union { __hip_bfloat162 h2[4]; short8v v; } pk_;                       \
      _Pragma("unroll")                                                      \
      for (int j = 0; j < 4; ++j)                                            \
        pk_.h2[j] = __float22bfloat162_rn(make_float2(xm[rp][2*j], xm[rp][2*j+1])); \
      *reinterpret_cast<short8v*>(xT + slot_ * RS + xbyte_m) = pk_.v;        \
      psacc[gg][rp][jr_m] = ss_;                                             \
    }                                                                        \
    if (t < 32) {                                                            \
      const int ar_   = erp ? (ar1_) : (ar0_);                               \
      const int slot_ = (ar_ + 7) % 6;                                       \
      float ss_ = 0.f;                                                       \
      _Pragma("unroll")                                                      \
      for (int j = 0; j < 8; ++j) ss_ = fmaf(xe[j], xe[j], ss_);             \
      union { __hip_bfloat162 h2[4]; short8v v; } pk_;                       \
      _Pragma("unroll")                                                      \
      for (int j = 0; j < 4; ++j)                                            \
        pk_.h2[j] = __float22bfloat162_rn(make_float2(xe[2*j], xe[2*j+1]));  \
      *reinterpret_cast<short8v*>(xT + slot_ * RS + e_xbyte) = pk_.v;        \
      psacc[eg][erp][e_jr] = ss_;                                            \
    }                                                                        \
  }

#define REDUCE_SS(ar0_, ar1_)                                                \
  if (t < 132) {                                                             \
    const int rp_  = (t >= 66) ? 1 : 0;                                      \
    const int jr_  = t - 66 * rp_;                                           \
    const int ar_  = rp_ ? (ar1_) : (ar0_);                                  \
    const int slot_ = (ar_ + 7) % 6;                                         \
    float s_ = 0.f;                                                          \
    _Pragma("unroll")                                                        \
    for (int g2 = 0; g2 < 8; ++g2) s_ += psacc[g2][rp_][jr_];                \
    Ss[slot_][jr_] = s_;                                                     \
  }

  // ---- prologue: stage rows hs-1..hs+2 (2 batches) -------------------------
  STAGE_ISSUE(hs - 1, hs);
  STAGE_COMMIT(hs - 1, hs);
  __syncthreads();
  REDUCE_SS(hs - 1, hs);
  STAGE_ISSUE(hs + 1, hs + 2);
  __syncthreads();
  STAGE_COMMIT(hs + 1, hs + 2);
  __syncthreads();
  REDUCE_SS(hs + 1, hs + 2);
  __syncthreads();

  // ---- main loop: 4 h-pairs ------------------------------------------------
  const int jbase = wm * 32 + lr;
#pragma unroll 1
  for (int hp = 0; hp < 4; ++hp) {
    const int h0 = hs + 2 * hp;
    const bool last = (hp == 3);

    if (!last) STAGE_ISSUE(h0 + 3, h0 + 4);

    int soff[4];
#pragma unroll
    for (int r = 0; r < 4; ++r) soff[r] = ((h0 + 6 + r) % 6) * RS;

    float4v acc[2][2][2];
#pragma unroll
    for (int o = 0; o < 2; ++o)
#pragma unroll
      for (int ml = 0; ml < 2; ++ml)
#pragma unroll
        for (int nl = 0; nl < 2; ++nl) acc[o][ml][nl] = float4v{0.f, 0.f, 0.f, 0.f};

#pragma unroll
    for (int s = 0; s < 6; ++s) {
      const int kw    = s >> 1;
      const int half  = s & 1;
      const int cslot = half * 4 + lg;
      const int jlow  = (lr + kw) & 7;
      const int base_s = (jbase + kw) * 128 + ((cslot * 16) ^ (jlow << 4));
      short8v bfr[3][2];
#pragma unroll
      for (int r = 0; r < 3; ++r) {
        const int fi = (r * 6 + s) * 8 + wn * 2;
        bfr[r][0] = *reinterpret_cast<const short8v*>(wf + (size_t)(fi + 0) * 512 + l * 8);
        bfr[r][1] = *reinterpret_cast<const short8v*>(wf + (size_t)(fi + 1) * 512 + l * 8);
      }
#pragma unroll
      for (int r = 0; r < 4; ++r) {
        short8v a[2];
#pragma unroll
        for (int ml = 0; ml < 2; ++ml)
          a[ml] = *reinterpret_cast<const short8v*>(xT + soff[r] + base_s + ml * 2048);
        if (r < 3) {
#pragma unroll
          for (int ml = 0; ml < 2; ++ml)
#pragma unroll
            for (int nl = 0; nl < 2; ++nl)
              acc[0][ml][nl] = __builtin_amdgcn_mfma_f32_16x16x32_bf16(
                  a[ml], bfr[r][nl], acc[0][ml][nl], 0, 0, 0);
        }
        if (r >= 1) {
#pragma unroll
          for (int ml = 0; ml < 2; ++ml)
#pragma unroll
            for (int nl = 0; nl < 2; ++nl)
              acc[1][ml][nl] = __builtin_amdgcn_mfma_f32_16x16x32_bf16(
                  a[ml], bfr[r - 1][nl], acc[1][ml][nl], 0, 0, 0);
        }
      }
    }

    // per-thread pl from Ss (window rows h0-1..h0+2)
    float plr[2][2][4];
#pragma unroll
    for (int ml = 0; ml < 2; ++ml) {
      const int base = wm * 32 + ml * 16 + lg * 4;
      float cs[4][4];
#pragma unroll
      for (int rr = 0; rr < 4; ++rr) {
        const float* Sr = Ss[(h0 + 6 + rr) % 6];
        const float v0 = Sr[base],     v1 = Sr[base + 1], v2 = Sr[base + 2];
        const float v3 = Sr[base + 3], v4 = Sr[base + 4], v5 = Sr[base + 5];
        cs[rr][0] = v0 + v1 + v2;  cs[rr][1] = v1 + v2 + v3;
        cs[rr][2] = v2 + v3 + v4;  cs[rr][3] = v3 + v4 + v5;
      }
#pragma unroll
      for (int r = 0; r < 4; ++r) {
        const float P0 = cs[0][r] + cs[1][r] + cs[2][r];
        const float P1 = cs[1][r] + cs[2][r] + cs[3][r];
        plr[0][ml][r] = pe * (nlg_nkq - __builtin_amdgcn_logf(sqrtf(P0) + qe));
        plr[1][ml][r] = pe * (nlg_nkq - __builtin_amdgcn_logf(sqrtf(P1) + qe));
      }
    }

    if (!last) STAGE_COMMIT(h0 + 3, h0 + 4);

    LGKM_BARRIER();                       // A: LDS writes visible; stores in flight

    if (!last) REDUCE_SS(h0 + 3, h0 + 4);

    // epilogue: out = copysign(exp2(fma(pe, log2|s|, pl)), s) + bias
#pragma unroll
    for (int o = 0; o < 2; ++o) {
      const int oh = h0 + o;
#pragma unroll
      for (int ml = 0; ml < 2; ++ml) {
        const int wloc = wm * 32 + ml * 16 + lg * 4;
#pragma unroll
        for (int nl = 0; nl < 2; ++nl) {
          const int n  = wn * 32 + nl * 16 + lr;
          const float bv = nl ? bv1 : bv0;
          float4v ov;
#pragma unroll
          for (int r = 0; r < 4; ++r) {
            const float sv  = acc[o][ml][nl][r];
            const float lg2 = __builtin_amdgcn_logf(fabsf(sv));
            const float e   = __builtin_amdgcn_exp2f(fmaf(pe, lg2, plr[o][ml][r]));
            ov[r] = copysignf(e, sv) + bv;
          }
          *reinterpret_cast<float4v*>(
              out + (((size_t)b * C_OUT + n) * H_N + oh) * W_N + w0 + wloc) = ov;
        }
      }
    }

    LGKM_BARRIER();                       // B: gate next iter's LDS reads
  }
}

// ---------------------------------------------------------------------------
extern "C" void kernel_launch(void* const* d_in, const int* in_sizes, int n_in,
                              void* d_out, int out_size, void* d_ws, size_t ws_size,
                              hipStream_t stream) {
  const float* x = (const float*)d_in[0];
  const float* w = (const float*)d_in[1];
  const float* b = (const float*)d_in[2];
  const float* q = (const float*)d_in[3];
  const float* p = (const float*)d_in[4];
  float* out = (float*)d_out;
  float* partial = (float*)d_ws;                               // 36 floats
  unsigned short* wf = (unsigned short*)((char*)d_ws + 256);   // 144KB B-frags

  scs_prep_w<<<36, 256, 0, stream>>>(w, wf, partial);
  scs_main<<<512, 512, 0, stream>>>(x, wf, b, q, p, partial, out);
}

// Round 14
// 111.872 us; speedup vs baseline: 2.1051x; 2.1051x over previous
//
#include <hip/hip_runtime.h>
#include <hip/hip_bf16.h>
#include <math.h>

#define B_N 16
#define C_IN 64
#define H_N 128
#define W_N 128
#define C_OUT 128
#define RS 8448      // bytes per row-slot: 66 cols * 128B
#define NSLOT 6

typedef __attribute__((ext_vector_type(8))) short short8v;   // 8 bf16
typedef __attribute__((ext_vector_type(4))) float float4v;

__device__ __forceinline__ unsigned short f2bf(float f) {
  union { float f; unsigned u; } c; c.f = f;
  unsigned u = c.u + 0x7fffu + ((c.u >> 16) & 1u);   // RNE
  return (unsigned short)(u >> 16);
}

// ---------------------------------------------------------------------------
// Prep: pack weights into per-lane B-fragment order (bf16) + w^2 partials.
// ---------------------------------------------------------------------------
__global__ __launch_bounds__(256) void scs_prep_w(
    const float* __restrict__ w, unsigned short* __restrict__ wf,
    float* __restrict__ partial)
{
  __shared__ float red[256];
  const int t    = threadIdx.x;
  const int gid  = blockIdx.x * 256 + t;
  const int frag = gid >> 6;
  const int l    = gid & 63;
  const int kh   = frag / 48;
  const int rem  = frag % 48;
  const int s    = rem >> 3;
  const int nt   = rem & 7;
  const int kb   = kh * 192 + s * 32 + (l >> 4) * 8;
  const int n    = nt * 16 + (l & 15);
  short8v pk;
  float ss = 0.f;
#pragma unroll
  for (int j = 0; j < 8; ++j) {
    const float v = w[(size_t)(kb + j) * C_OUT + n];
    ss = fmaf(v, v, ss);
    pk[j] = (short)f2bf(v);
  }
  *reinterpret_cast<short8v*>(wf + (size_t)frag * 512 + l * 8) = pk;
  red[t] = ss;
  __syncthreads();
  for (int off = 128; off > 0; off >>= 1) {
    if (t < off) red[t] += red[t + off];
    __syncthreads();
  }
  if (t == 0) partial[blockIdx.x] = red[0];
}

// ---------------------------------------------------------------------------
// Main v7b: pipelined 8-row strip, spill-fixed.
//   __launch_bounds__(512,2): 256-VGPR budget so issue-early staging regs
//   stay in registers (v7's (512,4)->64VGPR spilled -> 386MB scratch).
//   Edge columns load directly in COMMIT (32 threads, no issue-early regs).
// Per h-pair: issue loads(next2) -> MFMA(cur) -> pl -> commit(next) ->
//   [lgkm bar] -> SsReduce(next) -> epilogue(cur) -> [lgkm bar].
// ---------------------------------------------------------------------------
#define LGKM_BARRIER()                                   \
  do {                                                   \
    asm volatile("s_waitcnt lgkmcnt(0)" ::: "memory");   \
    __builtin_amdgcn_s_barrier();                        \
    asm volatile("" ::: "memory");                       \
  } while (0)

__global__ __launch_bounds__(512, 2) void scs_main(
    const float* __restrict__ x, const unsigned short* __restrict__ wf,
    const float* __restrict__ bias, const float* __restrict__ q,
    const float* __restrict__ p, const float* __restrict__ partial,
    float* __restrict__ out)
{
  __shared__ alignas(16) char xT[NSLOT * RS];   // 50688B
  __shared__ float psacc[8][2][66];             // 4224B
  __shared__ float Ss[NSLOT][66];               // 1584B  (total 56.5KB)

  const int t   = threadIdx.x;
  const int l   = t & 63;
  const int wid = t >> 6;
  const int wm  = wid >> 2;        // 0..1 (M half: 32 pixels)
  const int wn  = wid & 3;         // 0..3 (N quarter: 32 couts)
  const int lr  = l & 15;
  const int lg  = l >> 4;
  const int bid = blockIdx.x;
  const int swz = (bid & 7) * 64 + (bid >> 3);  // bijective XCD remap (512%8==0)
  const int b     = swz >> 5;
  const int strip = (swz >> 1) & 15;
  const int w0    = (swz & 1) << 6;
  const int hs    = strip << 3;

  // scalars once per block
  float ssum = 0.f;
#pragma unroll
  for (int i = 0; i < 36; ++i) ssum += partial[i];
  const float nk = sqrtf(ssum);
  const float qe = __builtin_amdgcn_exp2f(q[0] * 1.4426950408889634f);
  const float pe = __builtin_amdgcn_exp2f(p[0] * 1.4426950408889634f);
  const float nlg_nkq = -__builtin_amdgcn_logf(nk + qe);
  const float bv0 = bias[wn * 32 + lr];
  const float bv1 = bias[wn * 32 + 16 + lr];

  // staging maps
  const int wl = t & 63, gg = t >> 6;
  const int jr_m    = wl + 1;
  const int xbyte_m = jr_m * 128 + ((gg * 16) ^ ((jr_m & 7) << 4));
  const int ee  = t & 1, erp = (t >> 1) & 1, eg = t >> 2;  // for t<32
  const int e_jr    = ee ? 65 : 0;
  const int e_gw    = w0 - 1 + ee * 65;
  const int e_xbyte = e_jr * 128 + ((eg * 16) ^ ((e_jr & 7) << 4));

  float xm[2][8];

#define STAGE_ISSUE(ar0_, ar1_)                                              \
  {                                                                          \
    _Pragma("unroll")                                                        \
    for (int rp = 0; rp < 2; ++rp) {                                         \
      const int ar_ = rp ? (ar1_) : (ar0_);                                  \
      if ((unsigned)ar_ < 128u) {                                            \
        const float* src_ = x + (((size_t)b * C_IN + gg * 8) * H_N + ar_) * W_N + w0 + wl; \
        _Pragma("unroll")                                                    \
        for (int j = 0; j < 8; ++j) xm[rp][j] = src_[(size_t)j * H_N * W_N]; \
      } else {                                                               \
        _Pragma("unroll")                                                    \
        for (int j = 0; j < 8; ++j) xm[rp][j] = 0.f;                         \
      }                                                                      \
    }                                                                        \
  }

#define STAGE_COMMIT(ar0_, ar1_)                                             \
  {                                                                          \
    _Pragma("unroll")                                                        \
    for (int rp = 0; rp < 2; ++rp) {                                         \
      const int ar_   = rp ? (ar1_) : (ar0_);                                \
      const int slot_ = (ar_ + 7) % 6;                                       \
      float ss_ = 0.f;                                                       \
      _Pragma("unroll")                                                      \
      for (int j = 0; j < 8; ++j) ss_ = fmaf(xm[rp][j], xm[rp][j], ss_);     \
      union { __hip_bfloat162 h2[4]; short8v v; } pk_;                       \
      _Pragma("unroll")                                                      \
      for (int j = 0; j < 4; ++j)                                            \
        pk_.h2[j] = __float22bfloat162_rn(make_float2(xm[rp][2*j], xm[rp][2*j+1])); \
      *reinterpret_cast<short8v*>(xT + slot_ * RS + xbyte_m) = pk_.v;        \
      psacc[gg][rp][jr_m] = ss_;                                             \
    }                                                                        \
    if (t < 32) {                                                            \
      const int ar_   = erp ? (ar1_) : (ar0_);                               \
      const int slot_ = (ar_ + 7) % 6;                                       \
      float ss_ = 0.f;                                                       \
      union { __hip_bfloat162 h2[4]; short8v v; } pk_;                       \
      if (((unsigned)ar_ < 128u) && ((unsigned)e_gw < 128u)) {               \
        const float* src_ = x + (((size_t)b * C_IN + eg * 8) * H_N + ar_) * W_N + e_gw; \
        float xv_[8];                                                        \
        _Pragma("unroll")                                                    \
        for (int j = 0; j < 8; ++j) xv_[j] = src_[(size_t)j * H_N * W_N];    \
        _Pragma("unroll")                                                    \
        for (int j = 0; j < 8; ++j) ss_ = fmaf(xv_[j], xv_[j], ss_);         \
        _Pragma("unroll")                                                    \
        for (int j = 0; j < 4; ++j)                                          \
          pk_.h2[j] = __float22bfloat162_rn(make_float2(xv_[2*j], xv_[2*j+1])); \
      } else {                                                               \
        _Pragma("unroll")                                                    \
        for (int j = 0; j < 4; ++j)                                          \
          pk_.h2[j] = __float22bfloat162_rn(make_float2(0.f, 0.f));          \
      }                                                                      \
      *reinterpret_cast<short8v*>(xT + slot_ * RS + e_xbyte) = pk_.v;        \
      psacc[eg][erp][e_jr] = ss_;                                            \
    }                                                                        \
  }

#define REDUCE_SS(ar0_, ar1_)                                                \
  if (t < 132) {                                                             \
    const int rp_  = (t >= 66) ? 1 : 0;                                      \
    const int jr_  = t - 66 * rp_;                                           \
    const int ar_  = rp_ ? (ar1_) : (ar0_);                                  \
    const int slot_ = (ar_ + 7) % 6;                                         \
    float s_ = 0.f;                                                          \
    _Pragma("unroll")                                                        \
    for (int g2 = 0; g2 < 8; ++g2) s_ += psacc[g2][rp_][jr_];                \
    Ss[slot_][jr_] = s_;                                                     \
  }

  // ---- prologue: stage rows hs-1..hs+2 (2 batches) -------------------------
  STAGE_ISSUE(hs - 1, hs);
  STAGE_COMMIT(hs - 1, hs);
  __syncthreads();
  REDUCE_SS(hs - 1, hs);
  STAGE_ISSUE(hs + 1, hs + 2);
  __syncthreads();
  STAGE_COMMIT(hs + 1, hs + 2);
  __syncthreads();
  REDUCE_SS(hs + 1, hs + 2);
  __syncthreads();

  // ---- main loop: 4 h-pairs ------------------------------------------------
  const int jbase = wm * 32 + lr;
#pragma unroll 1
  for (int hp = 0; hp < 4; ++hp) {
    const int h0 = hs + 2 * hp;
    const bool last = (hp == 3);

    if (!last) STAGE_ISSUE(h0 + 3, h0 + 4);

    int soff[4];
#pragma unroll
    for (int r = 0; r < 4; ++r) soff[r] = ((h0 + 6 + r) % 6) * RS;

    float4v acc[2][2][2];
#pragma unroll
    for (int o = 0; o < 2; ++o)
#pragma unroll
      for (int ml = 0; ml < 2; ++ml)
#pragma unroll
        for (int nl = 0; nl < 2; ++nl) acc[o][ml][nl] = float4v{0.f, 0.f, 0.f, 0.f};

#pragma unroll
    for (int s = 0; s < 6; ++s) {
      const int kw    = s >> 1;
      const int half  = s & 1;
      const int cslot = half * 4 + lg;
      const int jlow  = (lr + kw) & 7;
      const int base_s = (jbase + kw) * 128 + ((cslot * 16) ^ (jlow << 4));
      short8v bfr[3][2];
#pragma unroll
      for (int r = 0; r < 3; ++r) {
        const int fi = (r * 6 + s) * 8 + wn * 2;
        bfr[r][0] = *reinterpret_cast<const short8v*>(wf + (size_t)(fi + 0) * 512 + l * 8);
        bfr[r][1] = *reinterpret_cast<const short8v*>(wf + (size_t)(fi + 1) * 512 + l * 8);
      }
#pragma unroll
      for (int r = 0; r < 4; ++r) {
        short8v a[2];
#pragma unroll
        for (int ml = 0; ml < 2; ++ml)
          a[ml] = *reinterpret_cast<const short8v*>(xT + soff[r] + base_s + ml * 2048);
        if (r < 3) {
#pragma unroll
          for (int ml = 0; ml < 2; ++ml)
#pragma unroll
            for (int nl = 0; nl < 2; ++nl)
              acc[0][ml][nl] = __builtin_amdgcn_mfma_f32_16x16x32_bf16(
                  a[ml], bfr[r][nl], acc[0][ml][nl], 0, 0, 0);
        }
        if (r >= 1) {
#pragma unroll
          for (int ml = 0; ml < 2; ++ml)
#pragma unroll
            for (int nl = 0; nl < 2; ++nl)
              acc[1][ml][nl] = __builtin_amdgcn_mfma_f32_16x16x32_bf16(
                  a[ml], bfr[r - 1][nl], acc[1][ml][nl], 0, 0, 0);
        }
      }
    }

    // per-thread pl from Ss (window rows h0-1..h0+2)
    float plr[2][2][4];
#pragma unroll
    for (int ml = 0; ml < 2; ++ml) {
      const int base = wm * 32 + ml * 16 + lg * 4;
      float cs[4][4];
#pragma unroll
      for (int rr = 0; rr < 4; ++rr) {
        const float* Sr = Ss[(h0 + 6 + rr) % 6];
        const float v0 = Sr[base],     v1 = Sr[base + 1], v2 = Sr[base + 2];
        const float v3 = Sr[base + 3], v4 = Sr[base + 4], v5 = Sr[base + 5];
        cs[rr][0] = v0 + v1 + v2;  cs[rr][1] = v1 + v2 + v3;
        cs[rr][2] = v2 + v3 + v4;  cs[rr][3] = v3 + v4 + v5;
      }
#pragma unroll
      for (int r = 0; r < 4; ++r) {
        const float P0 = cs[0][r] + cs[1][r] + cs[2][r];
        const float P1 = cs[1][r] + cs[2][r] + cs[3][r];
        plr[0][ml][r] = pe * (nlg_nkq - __builtin_amdgcn_logf(sqrtf(P0) + qe));
        plr[1][ml][r] = pe * (nlg_nkq - __builtin_amdgcn_logf(sqrtf(P1) + qe));
      }
    }

    if (!last) STAGE_COMMIT(h0 + 3, h0 + 4);

    LGKM_BARRIER();                       // A: LDS writes visible; stores in flight

    if (!last) REDUCE_SS(h0 + 3, h0 + 4);

    // epilogue: out = copysign(exp2(fma(pe, log2|s|, pl)), s) + bias
#pragma unroll
    for (int o = 0; o < 2; ++o) {
      const int oh = h0 + o;
#pragma unroll
      for (int ml = 0; ml < 2; ++ml) {
        const int wloc = wm * 32 + ml * 16 + lg * 4;
#pragma unroll
        for (int nl = 0; nl < 2; ++nl) {
          const int n  = wn * 32 + nl * 16 + lr;
          const float bv = nl ? bv1 : bv0;
          float4v ov;
#pragma unroll
          for (int r = 0; r < 4; ++r) {
            const float sv  = acc[o][ml][nl][r];
            const float lg2 = __builtin_amdgcn_logf(fabsf(sv));
            const float e   = __builtin_amdgcn_exp2f(fmaf(pe, lg2, plr[o][ml][r]));
            ov[r] = copysignf(e, sv) + bv;
          }
          *reinterpret_cast<float4v*>(
              out + (((size_t)b * C_OUT + n) * H_N + oh) * W_N + w0 + wloc) = ov;
        }
      }
    }

    LGKM_BARRIER();                       // B: gate next iter's LDS reads
  }
}

// ---------------------------------------------------------------------------
extern "C" void kernel_launch(void* const* d_in, const int* in_sizes, int n_in,
                              void* d_out, int out_size, void* d_ws, size_t ws_size,
                              hipStream_t stream) {
  const float* x = (const float*)d_in[0];
  const float* w = (const float*)d_in[1];
  const float* b = (const float*)d_in[2];
  const float* q = (const float*)d_in[3];
  const float* p = (const float*)d_in[4];
  float* out = (float*)d_out;
  float* partial = (float*)d_ws;                               // 36 floats
  unsigned short* wf = (unsigned short*)((char*)d_ws + 256);   // 144KB B-frags

  scs_prep_w<<<36, 256, 0, stream>>>(w, wf, partial);
  scs_main<<<512, 512, 0, stream>>>(x, wf, b, q, p, partial, out);
}

// Round 15
// 89.406 us; speedup vs baseline: 2.6341x; 1.2513x over previous
//
#include <hip/hip_runtime.h>
#include <hip/hip_bf16.h>
#include <math.h>

#define B_N 16
#define C_IN 64
#define H_N 128
#define W_N 128
#define C_OUT 128

typedef __attribute__((ext_vector_type(8))) short short8v;   // 8 bf16
typedef __attribute__((ext_vector_type(4))) float float4v;
typedef __attribute__((ext_vector_type(4))) unsigned int uint4v;

__device__ __forceinline__ unsigned short f2bf(float f) {
  union { float f; unsigned u; } c; c.f = f;
  unsigned u = c.u + 0x7fffu + ((c.u >> 16) & 1u);   // RNE
  return (unsigned short)(u >> 16);
}

// ws layout
#define WS_WF_OFF    256                      // 147456B of B-frags
#define WS_XTG_OFF   151552                   // 34,611,200B xTg
#define WS_SROWC_OFF (151552 + 34611200)      // 1,064,960B SrowC
#define WS_NEED      (WS_SROWC_OFF + 1064960)
// xTg: [b][hrow 0..129][cslot 0..7][wslot 0..129][8ci] bf16; 8320 ushort/(b,hrow)
// SrowC: [b][hrow 0..129][w 0..127] fp32 (3-col-summed channel sq-sums)

// ---------------------------------------------------------------------------
// Prep W: pack weights into per-lane B-fragment order (bf16) + w^2 partials.
// ---------------------------------------------------------------------------
__global__ __launch_bounds__(256) void scs_prep_w(
    const float* __restrict__ w, unsigned short* __restrict__ wf,
    float* __restrict__ partial)
{
  __shared__ float red[256];
  const int t    = threadIdx.x;
  const int gid  = blockIdx.x * 256 + t;
  const int frag = gid >> 6;
  const int l    = gid & 63;
  const int kh   = frag / 48;
  const int rem  = frag % 48;
  const int s    = rem >> 3;
  const int nt   = rem & 7;
  const int kb   = kh * 192 + s * 32 + (l >> 4) * 8;
  const int n    = nt * 16 + (l & 15);
  short8v pk;
  float ss = 0.f;
#pragma unroll
  for (int j = 0; j < 8; ++j) {
    const float v = w[(size_t)(kb + j) * C_OUT + n];
    ss = fmaf(v, v, ss);
    pk[j] = (short)f2bf(v);
  }
  *reinterpret_cast<short8v*>(wf + (size_t)frag * 512 + l * 8) = pk;
  red[t] = ss;
  __syncthreads();
  for (int off = 128; off > 0; off >>= 1) {
    if (t < off) red[t] += red[t + off];
    __syncthreads();
  }
  if (t == 0) partial[blockIdx.x] = red[0];
}

// ---------------------------------------------------------------------------
// Prep X: transpose x -> xTg (bf16, fragment-native, zero-padded) + SrowC.
// grid 16*130 blocks (b, hrow), 256 threads.
// ---------------------------------------------------------------------------
__global__ __launch_bounds__(256) void scs_prep_x(
    const float* __restrict__ x, unsigned short* __restrict__ xTg,
    float* __restrict__ SrowC)
{
  __shared__ float ps[2][128];
  __shared__ float Srow[128];

  const int t    = threadIdx.x;
  const int bidx = blockIdx.x;
  const int b    = bidx / 130;
  const int hrow = bidx % 130;
  const int h    = hrow - 1;
  unsigned short* rowp = xTg + (size_t)(b * 130 + hrow) * 8320;
  float* srp = SrowC + (size_t)(b * 130 + hrow) * 128;

  if (h < 0 || h >= H_N) {           // pad row: zero everything
    for (int i = t; i < 1040; i += 256)
      *reinterpret_cast<short8v*>(rowp + i * 8) = short8v{0,0,0,0,0,0,0,0};
    if (t < 128) srp[t] = 0.f;
    return;
  }

  const int w = t & 127, chalf = t >> 7;
  float v[32];
  const float* src = x + (((size_t)b * C_IN + chalf * 32) * H_N + h) * W_N + w;
#pragma unroll
  for (int j = 0; j < 32; ++j) v[j] = src[(size_t)j * H_N * W_N];
  float ss = 0.f;
#pragma unroll
  for (int j = 0; j < 32; ++j) ss = fmaf(v[j], v[j], ss);
  ps[chalf][w] = ss;

  // pack + store 4 cslots (16B each, lanes coalesced over w)
#pragma unroll
  for (int c4 = 0; c4 < 4; ++c4) {
    const int cslot = chalf * 4 + c4;
    union { __hip_bfloat162 h2[4]; short8v v8; } pk;
#pragma unroll
    for (int k = 0; k < 4; ++k)
      pk.h2[k] = __float22bfloat162_rn(make_float2(v[c4 * 8 + 2 * k], v[c4 * 8 + 2 * k + 1]));
    *reinterpret_cast<short8v*>(rowp + ((size_t)cslot * 130 + w + 1) * 8) = pk.v8;
  }
  // zero pads wslot 0 / 129 for all cslots
  if (t < 16) {
    const int cslot = t >> 1;
    const int wsl   = (t & 1) ? 129 : 0;
    *reinterpret_cast<short8v*>(rowp + ((size_t)cslot * 130 + wsl) * 8) =
        short8v{0,0,0,0,0,0,0,0};
  }
  __syncthreads();
  if (t < 128) Srow[t] = ps[0][t] + ps[1][t];
  __syncthreads();
  if (t < 128) {
    const float lft = (t > 0)   ? Srow[t - 1] : 0.f;
    const float rgt = (t < 127) ? Srow[t + 1] : 0.f;
    srp[t] = lft + Srow[t] + rgt;
  }
}

// ---------------------------------------------------------------------------
// Main M: block = (b, h-pair, w-half). 2048 blocks, 512 threads, LDS 512B.
// A-frags: direct global 16B loads from xTg; B-frags from wf; one barrier.
// ---------------------------------------------------------------------------
__global__ __launch_bounds__(512, 4) void scs_mainM(
    const unsigned short* __restrict__ xTg, const unsigned short* __restrict__ wf,
    const float* __restrict__ SrowC, const float* __restrict__ bias,
    const float* __restrict__ q, const float* __restrict__ p,
    const float* __restrict__ partial, float* __restrict__ out)
{
  __shared__ float pl[2][64];

  const int t   = threadIdx.x;
  const int l   = t & 63;
  const int wid = t >> 6;
  const int wm  = wid >> 2;        // 0..1  (32-pixel half of the 64)
  const int wn  = wid & 3;         // 0..3  (32-cout quarter)
  const int lr  = l & 15;
  const int lg  = l >> 4;
  const int bid = blockIdx.x;
  const int swz = (bid & 7) * 256 + (bid >> 3);   // bijective XCD remap
  const int b   = swz >> 7;
  const int hp  = (swz & 127) >> 1;
  const int w0  = (swz & 1) << 6;
  const int h0  = hp << 1;

  // scalars (uniform, cached)
  float ssum = 0.f;
#pragma unroll
  for (int i = 0; i < 36; ++i) ssum += partial[i];
  const float nk = sqrtf(ssum);
  const float qe = __builtin_amdgcn_exp2f(q[0] * 1.4426950408889634f);
  const float pe = __builtin_amdgcn_exp2f(p[0] * 1.4426950408889634f);
  const float nlg_nkq = -__builtin_amdgcn_logf(nk + qe);
  const float bv0 = bias[wn * 32 + lr];
  const float bv1 = bias[wn * 32 + 16 + lr];

  // per-pixel pl (3 SrowC reads each)
  if (t < 128) {
    const int o = t >> 6, wl = t & 63;
    const float* sp = SrowC + ((size_t)(b * 130 + h0 + o) * 128) + w0 + wl;
    const float P = sp[0] + sp[128] + sp[256];
    pl[o][wl] = pe * (nlg_nkq - __builtin_amdgcn_logf(sqrtf(P) + qe));
  }
  __syncthreads();

  // ---- MFMA: A direct from xTg -------------------------------------------
  float4v acc[2][2][2];
#pragma unroll
  for (int o = 0; o < 2; ++o)
#pragma unroll
    for (int ml = 0; ml < 2; ++ml)
#pragma unroll
      for (int nl = 0; nl < 2; ++nl) acc[o][ml][nl] = float4v{0.f, 0.f, 0.f, 0.f};

  const unsigned short* abase = xTg + (size_t)(b * 130 + h0) * 8320;
  const int jbase = w0 + wm * 32 + lr;
#pragma unroll
  for (int s = 0; s < 6; ++s) {
    const int kw    = s >> 1;
    const int cslot = (s & 1) * 4 + lg;
    const int off_s = (cslot * 130 + jbase + kw) * 8;
    short8v bfr[3][2];
#pragma unroll
    for (int r = 0; r < 3; ++r) {
      const int fi = (r * 6 + s) * 8 + wn * 2;
      bfr[r][0] = *reinterpret_cast<const short8v*>(wf + (size_t)(fi + 0) * 512 + l * 8);
      bfr[r][1] = *reinterpret_cast<const short8v*>(wf + (size_t)(fi + 1) * 512 + l * 8);
    }
#pragma unroll
    for (int r = 0; r < 4; ++r) {
      short8v a[2];
#pragma unroll
      for (int ml = 0; ml < 2; ++ml)
        a[ml] = *reinterpret_cast<const short8v*>(abase + (size_t)r * 8320 + off_s + ml * 128);
      if (r < 3) {
#pragma unroll
        for (int ml = 0; ml < 2; ++ml)
#pragma unroll
          for (int nl = 0; nl < 2; ++nl)
            acc[0][ml][nl] = __builtin_amdgcn_mfma_f32_16x16x32_bf16(
                a[ml], bfr[r][nl], acc[0][ml][nl], 0, 0, 0);
      }
      if (r >= 1) {
#pragma unroll
        for (int ml = 0; ml < 2; ++ml)
#pragma unroll
          for (int nl = 0; nl < 2; ++nl)
            acc[1][ml][nl] = __builtin_amdgcn_mfma_f32_16x16x32_bf16(
                a[ml], bfr[r - 1][nl], acc[1][ml][nl], 0, 0, 0);
      }
    }
  }

  // ---- epilogue ------------------------------------------------------------
#pragma unroll
  for (int o = 0; o < 2; ++o) {
    const int oh = h0 + o;
#pragma unroll
    for (int ml = 0; ml < 2; ++ml) {
      const int wloc = wm * 32 + ml * 16 + lg * 4;
      const float4v plv = *reinterpret_cast<const float4v*>(&pl[o][wloc]);
#pragma unroll
      for (int nl = 0; nl < 2; ++nl) {
        const int n  = wn * 32 + nl * 16 + lr;
        const float bv = nl ? bv1 : bv0;
        float4v ov;
#pragma unroll
        for (int r = 0; r < 4; ++r) {
          const float sv  = acc[o][ml][nl][r];
          const float lg2 = __builtin_amdgcn_logf(fabsf(sv));
          const float e   = __builtin_amdgcn_exp2f(fmaf(pe, lg2, plv[r]));
          ov[r] = copysignf(e, sv) + bv;
        }
        *reinterpret_cast<float4v*>(
            out + (((size_t)b * C_OUT + n) * H_N + oh) * W_N + w0 + wloc) = ov;
      }
    }
  }
}

// ---------------------------------------------------------------------------
// Fallback (ws too small): proven v5 fused kernel (59.6us).
// ---------------------------------------------------------------------------
__global__ __launch_bounds__(512, 4) void scs_main_fb(
    const float* __restrict__ x, const unsigned short* __restrict__ wf,
    const float* __restrict__ bias, const float* __restrict__ q,
    const float* __restrict__ p, const float* __restrict__ partial,
    float* __restrict__ out)
{
  __shared__ alignas(16) char xT[4 * 16640];
  __shared__ float psacc[4][4][128];
  __shared__ float pl[2][128];

  const int t   = threadIdx.x;
  const int l   = t & 63;
  const int wid = t >> 6;
  const int wm  = wid >> 2;
  const int wn  = wid & 3;
  const int lr  = l & 15;
  const int lg  = l >> 4;
  const int bid = blockIdx.x;
  const int swz = (bid & 7) * 128 + (bid >> 3);
  const int b   = swz >> 6;
  const int h0  = (swz & 63) << 1;

  if (t < 64) {
    const int k   = t >> 3;
    const int row = k >> 1;
    const int jr  = (k & 1) ? 129 : 0;
    *reinterpret_cast<float4v*>(xT + row * 16640 + jr * 128 + (t & 7) * 16) =
        float4v{0.f, 0.f, 0.f, 0.f};
  }

  const int wcol  = t & 127;
  const int cbase = t >> 7;
  float part0 = 0.f, part1 = 0.f, part2 = 0.f, part3 = 0.f;
#pragma unroll
  for (int it = 0; it < 8; ++it) {
    const int  row4  = it >> 1;
    const int  cc    = (it & 1) * 4 + cbase;
    const int  inr   = h0 - 1 + row4;
    const bool valid = (unsigned)inr < 128u;
    const int  jr    = wcol + 1;
    int byte = row4 * 16640 + jr * 128 + cc * 16;
    byte ^= (jr & 7) << 4;
    if (valid) {
      const float* src = x + (((size_t)b * C_IN + cc * 8) * H_N + inr) * W_N + wcol;
      float xv[8];
#pragma unroll
      for (int j = 0; j < 8; ++j) xv[j] = src[(size_t)j * H_N * W_N];
      float pp = 0.f;
#pragma unroll
      for (int j = 0; j < 8; ++j) pp = fmaf(xv[j], xv[j], pp);
      if      (row4 == 0) part0 += pp;
      else if (row4 == 1) part1 += pp;
      else if (row4 == 2) part2 += pp;
      else                part3 += pp;
      union { __hip_bfloat162 h2[4]; short8v v; } pk;
#pragma unroll
      for (int j = 0; j < 4; ++j)
        pk.h2[j] = __float22bfloat162_rn(make_float2(xv[2 * j], xv[2 * j + 1]));
      *reinterpret_cast<short8v*>(xT + byte) = pk.v;
    } else {
      *reinterpret_cast<short8v*>(xT + byte) = short8v{0,0,0,0,0,0,0,0};
    }
  }
  psacc[cbase][0][wcol] = part0;
  psacc[cbase][1][wcol] = part1;
  psacc[cbase][2][wcol] = part2;
  psacc[cbase][3][wcol] = part3;

  const float bv0 = bias[wn * 32 + lr];
  const float bv1 = bias[wn * 32 + 16 + lr];
  __syncthreads();

  float4v acc[2][4][2];
#pragma unroll
  for (int o = 0; o < 2; ++o)
#pragma unroll
    for (int ml = 0; ml < 4; ++ml)
#pragma unroll
      for (int nl = 0; nl < 2; ++nl) acc[o][ml][nl] = float4v{0.f, 0.f, 0.f, 0.f};

  const int jbase = wm * 64 + lr;
#pragma unroll
  for (int s = 0; s < 6; ++s) {
    const int kw    = s >> 1;
    const int half  = s & 1;
    const int cslot = half * 4 + lg;
    const int jlow  = (lr + kw) & 7;
    const int base_s = (jbase + kw) * 128 + ((cslot * 16) ^ (jlow << 4));
    short8v bfr[3][2];
#pragma unroll
    for (int r = 0; r < 3; ++r) {
      const int fi = (r * 6 + s) * 8 + wn * 2;
      bfr[r][0] = *reinterpret_cast<const short8v*>(wf + (size_t)(fi + 0) * 512 + l * 8);
      bfr[r][1] = *reinterpret_cast<const short8v*>(wf + (size_t)(fi + 1) * 512 + l * 8);
    }
#pragma unroll
    for (int r = 0; r < 4; ++r) {
      short8v a[4];
#pragma unroll
      for (int ml = 0; ml < 4; ++ml)
        a[ml] = *reinterpret_cast<const short8v*>(xT + base_s + r * 16640 + ml * 2048);
      if (r < 3) {
#pragma unroll
        for (int ml = 0; ml < 4; ++ml)
#pragma unroll
          for (int nl = 0; nl < 2; ++nl)
            acc[0][ml][nl] = __builtin_amdgcn_mfma_f32_16x16x32_bf16(
                a[ml], bfr[r][nl], acc[0][ml][nl], 0, 0, 0);
      }
      if (r >= 1) {
#pragma unroll
        for (int ml = 0; ml < 4; ++ml)
#pragma unroll
          for (int nl = 0; nl < 2; ++nl)
            acc[1][ml][nl] = __builtin_amdgcn_mfma_f32_16x16x32_bf16(
                a[ml], bfr[r - 1][nl], acc[1][ml][nl], 0, 0, 0);
      }
    }
  }

  float ssum = 0.f;
#pragma unroll
  for (int i = 0; i < 36; ++i) ssum += partial[i];
  const float nk = sqrtf(ssum);
  const float qe = __builtin_amdgcn_exp2f(q[0] * 1.4426950408889634f);
  const float pe = __builtin_amdgcn_exp2f(p[0] * 1.4426950408889634f);
  const float nlg_nkq = -__builtin_amdgcn_logf(nk + qe);

  if (t < 256) {
    const int o = t >> 7;
    const int w = t & 127;
    float P = 0.f;
#pragma unroll
    for (int dw = 0; dw < 3; ++dw) {
      const int ww = w + dw - 1;
      if ((unsigned)ww < 128u) {
#pragma unroll
        for (int rr = 0; rr < 3; ++rr)
#pragma unroll
          for (int cc = 0; cc < 4; ++cc)
            P += psacc[cc][o + rr][ww];
      }
    }
    pl[o][w] = pe * (nlg_nkq - __builtin_amdgcn_logf(sqrtf(P) + qe));
  }
  __syncthreads();

#pragma unroll
  for (int o = 0; o < 2; ++o) {
    const int oh = h0 + o;
#pragma unroll
    for (int ml = 0; ml < 4; ++ml) {
      const int w0 = wm * 64 + ml * 16 + lg * 4;
      const float4v plv = *reinterpret_cast<const float4v*>(&pl[o][w0]);
#pragma unroll
      for (int nl = 0; nl < 2; ++nl) {
        const int n  = wn * 32 + nl * 16 + lr;
        const float bv = nl ? bv1 : bv0;
        float4v ov;
#pragma unroll
        for (int r = 0; r < 4; ++r) {
          const float sv  = acc[o][ml][nl][r];
          const float lg2 = __builtin_amdgcn_logf(fabsf(sv));
          const float e   = __builtin_amdgcn_exp2f(fmaf(pe, lg2, plv[r]));
          ov[r] = copysignf(e, sv) + bv;
        }
        *reinterpret_cast<float4v*>(
            out + (((size_t)b * C_OUT + n) * H_N + oh) * W_N + w0) = ov;
      }
    }
  }
}

// ---------------------------------------------------------------------------
extern "C" void kernel_launch(void* const* d_in, const int* in_sizes, int n_in,
                              void* d_out, int out_size, void* d_ws, size_t ws_size,
                              hipStream_t stream) {
  const float* x = (const float*)d_in[0];
  const float* w = (const float*)d_in[1];
  const float* b = (const float*)d_in[2];
  const float* q = (const float*)d_in[3];
  const float* p = (const float*)d_in[4];
  float* out = (float*)d_out;
  float* partial = (float*)d_ws;
  unsigned short* wf = (unsigned short*)((char*)d_ws + WS_WF_OFF);

  scs_prep_w<<<36, 256, 0, stream>>>(w, wf, partial);

  if (ws_size >= (size_t)WS_NEED) {
    unsigned short* xTg = (unsigned short*)((char*)d_ws + WS_XTG_OFF);
    float* SrowC = (float*)((char*)d_ws + WS_SROWC_OFF);
    scs_prep_x<<<16 * 130, 256, 0, stream>>>(x, xTg, SrowC);
    scs_mainM<<<2048, 512, 0, stream>>>(xTg, wf, SrowC, b, q, p, partial, out);
  } else {
    scs_main_fb<<<B_N * (H_N / 2), 512, 0, stream>>>(x, wf, b, q, p, partial, out);
  }
}

// Round 17
// 62.345 us; speedup vs baseline: 3.7775x; 1.4341x over previous
//
#include <hip/hip_runtime.h>
#include <hip/hip_bf16.h>
#include <math.h>

#define B_N 16
#define C_IN 64
#define H_N 128
#define W_N 128
#define C_OUT 128
#define RS 8448       // bytes per row-slot: 66 cols * 128B

typedef __attribute__((ext_vector_type(8))) short short8v;   // 8 bf16
typedef __attribute__((ext_vector_type(4))) float float4v;

__device__ __forceinline__ unsigned short f2bf(float f) {
  union { float f; unsigned u; } c; c.f = f;
  unsigned u = c.u + 0x7fffu + ((c.u >> 16) & 1u);   // RNE
  return (unsigned short)(u >> 16);
}

// ---------------------------------------------------------------------------
// Prep W: pack weights into per-lane B-fragment order (bf16) + w^2 partials.
// frag id = (kh*6 + s)*8 + nt ; lane l supplies B[k=s*32+(l>>4)*8+j][n=nt*16+(l&15)]
// ---------------------------------------------------------------------------
__global__ __launch_bounds__(256) void scs_prep_w(
    const float* __restrict__ w, unsigned short* __restrict__ wf,
    float* __restrict__ partial)
{
  __shared__ float red[256];
  const int t    = threadIdx.x;
  const int gid  = blockIdx.x * 256 + t;
  const int frag = gid >> 6;
  const int l    = gid & 63;
  const int kh   = frag / 48;
  const int rem  = frag % 48;
  const int s    = rem >> 3;
  const int nt   = rem & 7;
  const int kb   = kh * 192 + s * 32 + (l >> 4) * 8;
  const int n    = nt * 16 + (l & 15);
  short8v pk;
  float ss = 0.f;
#pragma unroll
  for (int j = 0; j < 8; ++j) {
    const float v = w[(size_t)(kb + j) * C_OUT + n];
    ss = fmaf(v, v, ss);
    pk[j] = (short)f2bf(v);
  }
  *reinterpret_cast<short8v*>(wf + (size_t)frag * 512 + l * 8) = pk;
  red[t] = ss;
  __syncthreads();
  for (int off = 128; off > 0; off >>= 1) {
    if (t < off) red[t] += red[t + off];
    __syncthreads();
  }
  if (t == 0) partial[blockIdx.x] = red[0];
}

// ---------------------------------------------------------------------------
// Main v8 (H4): block = (b, 4 output rows, w-half). 1024 blocks, 512 threads.
// Stage 6 input rows x 66 cols (bf16, XOR-swizzled) + fp32 sq-sums -> barrier
// -> MFMA (slot r feeds o=r-kh for kh=0..2; 48 MFMA & 12 ds_read_b128 per s)
// -> pl (per-pixel log-domain scale) -> barrier -> epilogue.
// Staging/output ratio 1.5 rows/out vs v5's 2.0; 4 MFMA per ds_read vs 3.
// A-read geometry: local pixel p, kernel col kw -> LDS col jr = p+kw
// (col jr holds global pixel w0-1+jr, so patch element gw = w0+p-1+kw). ✓
// ---------------------------------------------------------------------------
__global__ __launch_bounds__(512, 4) void scs_main(
    const float* __restrict__ x, const unsigned short* __restrict__ wf,
    const float* __restrict__ bias, const float* __restrict__ q,
    const float* __restrict__ p, const float* __restrict__ partial,
    float* __restrict__ out)
{
  __shared__ alignas(16) char xT[6 * RS];      // 50688B
  __shared__ float psacc[8][6][66];            // 12672B  [cgroup][slot][col]
  __shared__ float pl[4][64];                  // 1024B   (total 64384B)

  const int t   = threadIdx.x;
  const int l   = t & 63;
  const int wid = t >> 6;
  const int wm  = wid >> 2;        // 0..1 (32-pixel half of 64)
  const int wn  = wid & 3;         // 0..3 (32-cout quarter)
  const int lr  = l & 15;
  const int lg  = l >> 4;
  const int bid = blockIdx.x;
  const int swz = (bid & 7) * 128 + (bid >> 3);   // bijective XCD remap (1024%8==0)
  const int b   = swz >> 6;
  const int rem = swz & 63;
  const int hs  = (rem >> 1) << 2;               // 0,4,...,124
  const int w0  = (rem & 1) << 6;                // 0 or 64

  // ---- stage 6 input rows -> bf16 xT (swizzled); fp32 squares --------------
  const int wl = t & 63, gg = t >> 6;
  {
    const int jr = wl + 1;
    const int xb = jr * 128 + ((gg * 16) ^ ((jr & 7) << 4));
#pragma unroll
    for (int r = 0; r < 6; ++r) {
      const int  inr   = hs - 1 + r;
      const bool valid = (unsigned)inr < 128u;   // block-uniform
      float ss = 0.f;
      if (valid) {
        const float* src = x + (((size_t)b * C_IN + gg * 8) * H_N + inr) * W_N + w0 + wl;
        float xv[8];
#pragma unroll
        for (int j = 0; j < 8; ++j) xv[j] = src[(size_t)j * H_N * W_N];
#pragma unroll
        for (int j = 0; j < 8; ++j) ss = fmaf(xv[j], xv[j], ss);
        union { __hip_bfloat162 h2[4]; short8v v; } pk;
#pragma unroll
        for (int j = 0; j < 4; ++j)
          pk.h2[j] = __float22bfloat162_rn(make_float2(xv[2 * j], xv[2 * j + 1]));
        *reinterpret_cast<short8v*>(xT + r * RS + xb) = pk.v;
      } else {
        *reinterpret_cast<short8v*>(xT + r * RS + xb) = short8v{0,0,0,0,0,0,0,0};
      }
      psacc[gg][r][jr] = ss;
    }
  }
  // edge columns: 96 threads, one (slot, edge, cgroup) cell each
  if (t < 96) {
    const int re  = t >> 4;            // slot 0..5
    const int sub = t & 15;
    const int ee  = sub & 1;           // 0=left(jr0), 1=right(jr65)
    const int ge  = sub >> 1;          // cgroup 0..7
    const int jr  = ee ? 65 : 0;
    const int gw  = w0 - 1 + ee * 65;
    const int inr = hs - 1 + re;
    const bool valid = ((unsigned)inr < 128u) && ((unsigned)gw < 128u);
    const int xb = re * RS + jr * 128 + ((ge * 16) ^ ((jr & 7) << 4));
    float ss = 0.f;
    if (valid) {
      const float* src = x + (((size_t)b * C_IN + ge * 8) * H_N + inr) * W_N + gw;
      float xv[8];
#pragma unroll
      for (int j = 0; j < 8; ++j) xv[j] = src[(size_t)j * H_N * W_N];
#pragma unroll
      for (int j = 0; j < 8; ++j) ss = fmaf(xv[j], xv[j], ss);
      union { __hip_bfloat162 h2[4]; short8v v; } pk;
#pragma unroll
      for (int j = 0; j < 4; ++j)
        pk.h2[j] = __float22bfloat162_rn(make_float2(xv[2 * j], xv[2 * j + 1]));
      *reinterpret_cast<short8v*>(xT + xb) = pk.v;
    } else {
      *reinterpret_cast<short8v*>(xT + xb) = short8v{0,0,0,0,0,0,0,0};
    }
    psacc[ge][re][jr] = ss;
  }

  // bias preload (overlaps barrier)
  const float bv0 = bias[wn * 32 + lr];
  const float bv1 = bias[wn * 32 + 16 + lr];

  __syncthreads();                               // xT + psacc ready

  // ---- MFMA: 6 K-steps (kw,cihalf); slot r feeds o = r-kh ------------------
  float4v acc[4][2][2];
#pragma unroll
  for (int o = 0; o < 4; ++o)
#pragma unroll
    for (int ml = 0; ml < 2; ++ml)
#pragma unroll
      for (int nl = 0; nl < 2; ++nl) acc[o][ml][nl] = float4v{0.f, 0.f, 0.f, 0.f};

  const int jbase = wm * 32 + lr;
#pragma unroll
  for (int s = 0; s < 6; ++s) {
    const int kw    = s >> 1;
    const int cslot = (s & 1) * 4 + lg;
    const int jlow  = (lr + kw) & 7;
    const int base_f = (jbase + kw) * 128 + ((cslot * 16) ^ (jlow << 4));

    short8v bfr[3][2];
#pragma unroll
    for (int kh = 0; kh < 3; ++kh) {
      const int fi = (kh * 6 + s) * 8 + wn * 2;
      bfr[kh][0] = *reinterpret_cast<const short8v*>(wf + (size_t)(fi + 0) * 512 + l * 8);
      bfr[kh][1] = *reinterpret_cast<const short8v*>(wf + (size_t)(fi + 1) * 512 + l * 8);
    }
#pragma unroll
    for (int r = 0; r < 6; ++r) {
      short8v a[2];
#pragma unroll
      for (int ml = 0; ml < 2; ++ml)
        a[ml] = *reinterpret_cast<const short8v*>(xT + r * RS + base_f + ml * 2048);
#pragma unroll
      for (int kh = 0; kh < 3; ++kh) {
        const int o = r - kh;
        if (o >= 0 && o < 4) {
#pragma unroll
          for (int ml = 0; ml < 2; ++ml)
#pragma unroll
            for (int nl = 0; nl < 2; ++nl)
              acc[o][ml][nl] = __builtin_amdgcn_mfma_f32_16x16x32_bf16(
                  a[ml], bfr[kh][nl], acc[o][ml][nl], 0, 0, 0);
        }
      }
    }
  }

  // ---- scalars + per-pixel pl ---------------------------------------------
  float ssum = 0.f;
#pragma unroll
  for (int i = 0; i < 36; ++i) ssum += partial[i];
  const float nk = sqrtf(ssum);
  const float qe = __builtin_amdgcn_exp2f(q[0] * 1.4426950408889634f);
  const float pe = __builtin_amdgcn_exp2f(p[0] * 1.4426950408889634f);
  const float nlg_nkq = -__builtin_amdgcn_logf(nk + qe);

  if (t < 256) {
    const int o   = t >> 6;        // 0..3
    const int wl2 = t & 63;
    const int jc  = wl2 + 1;       // patch cols jc-1, jc, jc+1
    float P = 0.f;
#pragma unroll
    for (int rr = 0; rr < 3; ++rr)
#pragma unroll
      for (int cc = 0; cc < 8; ++cc)
        P += psacc[cc][o + rr][jc - 1] + psacc[cc][o + rr][jc] + psacc[cc][o + rr][jc + 1];
    pl[o][wl2] = pe * (nlg_nkq - __builtin_amdgcn_logf(sqrtf(P) + qe));
  }
  __syncthreads();

  // ---- epilogue: out = copysign(exp2(fma(pe, log2|s|, pl)), s) + bias ------
#pragma unroll
  for (int o = 0; o < 4; ++o) {
    const int oh = hs + o;
#pragma unroll
    for (int ml = 0; ml < 2; ++ml) {
      const int wloc = wm * 32 + ml * 16 + lg * 4;
      const float4v plv = *reinterpret_cast<const float4v*>(&pl[o][wloc]);
#pragma unroll
      for (int nl = 0; nl < 2; ++nl) {
        const int n  = wn * 32 + nl * 16 + lr;
        const float bv = nl ? bv1 : bv0;
        float4v ov;
#pragma unroll
        for (int r = 0; r < 4; ++r) {
          const float sv  = acc[o][ml][nl][r];
          const float lg2 = __builtin_amdgcn_logf(fabsf(sv));
          const float e   = __builtin_amdgcn_exp2f(fmaf(pe, lg2, plv[r]));
          ov[r] = copysignf(e, sv) + bv;
        }
        *reinterpret_cast<float4v*>(
            out + (((size_t)b * C_OUT + n) * H_N + oh) * W_N + w0 + wloc) = ov;
      }
    }
  }
}

// ---------------------------------------------------------------------------
extern "C" void kernel_launch(void* const* d_in, const int* in_sizes, int n_in,
                              void* d_out, int out_size, void* d_ws, size_t ws_size,
                              hipStream_t stream) {
  const float* x = (const float*)d_in[0];
  const float* w = (const float*)d_in[1];
  const float* b = (const float*)d_in[2];
  const float* q = (const float*)d_in[3];
  const float* p = (const float*)d_in[4];
  float* out = (float*)d_out;
  float* partial = (float*)d_ws;                               // 36 floats
  unsigned short* wf = (unsigned short*)((char*)d_ws + 256);   // 144KB B-frags

  scs_prep_w<<<36, 256, 0, stream>>>(w, wf, partial);
  scs_main<<<B_N * (H_N / 4) * 2, 512, 0, stream>>>(x, wf, b, q, p, partial, out);
}